// Round 10
// baseline (174.596 us; speedup 1.0000x reference)
//
#include <hip/hip_runtime.h>
#include <stdint.h>

#define IN_F 512
#define OUT_F 512
#define NROWS 8192
#define NSLOT 12                 // 11 spline slots + 1 base(x) slot per in-feature
#define KTOT (IN_F * NSLOT)      // 6144
#define K16S (KTOT / 16)         // 384 k16-steps
#define SW_ROW (IN_F * 11)       // 5632 floats per output row of spline_weight
#define KC_PAD 776               // prep kcol row stride (ushorts)
#define AROWH 56                 // half-K A-tile row stride (ushorts): 48 slots + 8 pad
                                 // 112B rows stay 16B-aligned (R8 lesson); 4-way bank
                                 // pattern identical to the 96us anchor's AROW=120
#define ABUFH (128 * AROWH)      // 7168 ushorts per A buffer

typedef __bf16 bf16x8 __attribute__((ext_vector_type(8)));
typedef __bf16 bf16x2 __attribute__((ext_vector_type(2)));
typedef float f32x16 __attribute__((ext_vector_type(16)));

// frag-linear B: uint4 index (ntg*384 + k16)*64 + lane -> 8 bf16 =
//   B[k16*16+(lane>>5)*8+j][ntg*32 + (lane&31)],  k = f*12 + j_slot
__device__ ushort g_Wb[(K16S * 16 + 1) * 512];   // 6.3 MB

__device__ __forceinline__ ushort f2bf(float f) {
    uint32_t u = __builtin_bit_cast(uint32_t, f);
    u += 0x7FFFu + ((u >> 16) & 1u);          // RNE
    return (ushort)(u >> 16);
}

// ---- prep: weights -> frag-linear g_Wb, AND zero d_out (one dispatch) ------
__global__ __launch_bounds__(256) void prep_weights(const float* __restrict__ bw,
                                                    const float* __restrict__ sw,
                                                    float* __restrict__ out) {
    __shared__ __align__(16) ushort kcol[4 * KC_PAD];    // 6.2 KB
    const int t  = threadIdx.x;
    const int b  = blockIdx.x;
    const int nt = b & 15;                    // 32-out tile
    const int kg = (b >> 4) & 7;              // 64-feat group -> k16 [kg*48,+48)
    const int hq = b >> 7;                    // 0..7
    const int hv = hq >> 2;                   // out half (16 outs)
    const int qr = hq & 3;                    // quarter of the half (4 outs)
    const int o0 = nt * 32 + hv * 16 + qr * 4;
    const int f0 = kg * 64;

    // zero this block's slice of d_out (1024 float4 per block, coalesced)
    {
        float4* o4 = (float4*)out;
        const float4 z = make_float4(0.f, 0.f, 0.f, 0.f);
        #pragma unroll
        for (int i = 0; i < 4; ++i) o4[(size_t)b * 1024 + i * 256 + t] = z;
    }

    // phase 1: sw slices -> bf16 k-columns in LDS (4 rows x 704 floats)
    {
        const int o_l = t >> 6;               // 0..3
        const int tr  = t & 63;               // 64 threads per row
        const float* swr = sw + (size_t)(o0 + o_l) * SW_ROW + (size_t)f0 * 11;
        #pragma unroll
        for (int i = 0; i < 3; ++i) {
            int p4 = tr + i * 64;             // float4 idx 0..175
            if (p4 < 176) {
                float4 v = ((const float4*)swr)[p4];
                uint pos = (uint)p4 * 4;
                #pragma unroll
                for (int c = 0; c < 4; ++c) {
                    uint pc = pos + c;        // 0..703
                    uint fl = pc / 11u;
                    uint j  = pc - fl * 11u;
                    float val = (c == 0) ? v.x : (c == 1) ? v.y : (c == 2) ? v.z : v.w;
                    kcol[o_l * KC_PAD + fl * NSLOT + j] = f2bf(val);
                }
            }
        }
        // base weight -> slot 11 (64 feats, one per thread-in-row)
        kcol[o_l * KC_PAD + tr * NSLOT + 11] =
            f2bf(bw[(size_t)(o0 + o_l) * IN_F + f0 + tr]);
    }
    __syncthreads();

    // phase 2: frag-linear 16B stores (4 rows x 96 uint4 = 384 per block)
    {
        const int ol4 = t & 3;                // row within block
        const int ch  = t >> 2;               // 0..63
        #pragma unroll
        for (int i = 0; i < 2; ++i) {
            int idx = ch + i * 64;            // 0..127, valid < 96
            if (idx < 96) {
                int k16l = idx >> 1;
                int hf   = idx & 1;
                uint4 val = *(const uint4*)&kcol[ol4 * KC_PAD + k16l * 16 + hf * 8];
                ((uint4*)g_Wb)[((size_t)nt * K16S + kg * 48 + k16l) * 64
                               + hf * 32 + hv * 16 + qr * 4 + ol4] = val;
            }
        }
    }
}

// ---- basis eval: 12 bf16 slots packed into p[0..5] -------------------------
__device__ __forceinline__ void eval12(float xx, uint p[6]) {
    float wpos = (xx + 1.0f) * 7.0f;
    float fi = floorf(wpos);
    int   i  = (int)fi;
    float u  = wpos - fi;
    bool inr = (xx >= -1.0f) && (xx < 1.0f);
    int   q  = i - 3;
    float um = 1.0f - u;
    float uu = u * u, u3 = uu * u;
    const float C6 = 1.0f / 6.0f;
    float s0 = (inr && q >= 0) ? C6 : 0.0f;
    float s1 = (inr && q >= -1 && q <= 9) ? C6 : 0.0f;
    float s2 = (inr && q >= -2 && q <= 8) ? C6 : 0.0f;
    float s3 = (inr && q <= 7) ? C6 : 0.0f;
    float b0 = um * um * um * s0;
    float b1 = fmaf(3.0f, u3, fmaf(-6.0f, uu, 4.0f)) * s1;
    float b2 = fmaf(-3.0f, u3, fmaf(3.0f, uu, fmaf(3.0f, u, 1.0f))) * s2;
    float b3 = u3 * s3;
    bf16x2 k01; k01[0] = (__bf16)b0; k01[1] = (__bf16)b1;
    bf16x2 k23; k23[0] = (__bf16)b2; k23[1] = (__bf16)b3;
    uint K01 = __builtin_bit_cast(uint, k01);
    uint K23 = __builtin_bit_cast(uint, k23);
    int r  = q & 1;
    int e0 = q & ~1;
    uint P0 = r ? (K01 << 16) : K01;
    uint P1 = r ? ((K01 >> 16) | (K23 << 16)) : K23;
    uint P2 = r ? (K23 >> 16) : 0u;
    #pragma unroll
    for (int pi = 0; pi < 6; ++pi) {
        int d = 2 * pi - e0;
        p[pi] = (d == 0) ? P0 : (d == 2) ? P1 : (d == 4) ? P2 : 0u;
    }
    p[5] = (p[5] & 0xFFFFu) | ((uint)f2bf(xx) << 16);   // slot 11 = raw x
}

// stage 2 features -> 48 B via 6x ds_write_b64
__device__ __forceinline__ void stage2(float2 xv, ushort* dst) {
    uint p[2][6];
    eval12(xv.x, p[0]);
    eval12(xv.y, p[1]);
    #pragma unroll
    for (int c = 0; c < 2; ++c) {
        uint2 w0; w0.x = p[c][0]; w0.y = p[c][1];
        uint2 w1; w1.x = p[c][2]; w1.y = p[c][3];
        uint2 w2; w2.x = p[c][4]; w2.y = p[c][5];
        *(uint2*)&dst[c * 12 + 0] = w0;
        *(uint2*)&dst[c * 12 + 4] = w1;
        *(uint2*)&dst[c * 12 + 8] = w2;
    }
}

// ---- fused GEMM: block 128x128, half-K A double-buffer, 1 barrier/iter -----
// R10: restructured pipeline. K-tile halved (4 feats = 48 k), A dbuf fits in
// 28.7KB -> keeps 3 blocks/CU (R2's dbuf lost a block and regressed). Per iter:
//   issue 3 B-frag loads -> ds_read A(cur) -> stage A(g+1) (VALU, overlaps
//   other waves' MFMA) -> MFMA x12 -> __syncthreads.
// B loads are CONSUMED before the barrier, so the __syncthreads vmcnt(0) drain
// is ~free (only the 8-B x prefetch outstanding) — attacks the exposed B-L2
// latency WITHOUT asm barriers (R9: bar_lds -11%) and WITHOUT occupancy loss.
// Plain __syncthreads everywhere: no rule-18 ordering risk.
// grid 1024: bx = mb*16 + cg*4 + kp  ->  XCD = (cg*4+kp)%8: 2 cg/XCD (B L2-fit)
__global__ __launch_bounds__(256, 3) void kan_gemm(const float* __restrict__ x,
                                                   float* __restrict__ out) {
    __shared__ __align__(16) ushort As[2 * ABUFH];   // 28672 B

    const int t    = threadIdx.x;
    const int lane = t & 63;
    const int wv   = t >> 6;          // 0..3
    const int wr   = wv >> 1;         // wave M half
    const int wc   = wv & 1;          // wave N half
    const int ln31 = lane & 31;
    const int half = lane >> 5;

    const int bx = blockIdx.x;
    const int mb = bx >> 4;           // 0..63
    const int cg = (bx >> 2) & 3;     // 128-col group
    const int kp = bx & 3;            // K quarter (128 feats, 32 groups of 4)
    const int row_base = mb * 128;

    // staging: thread -> (row, 2 feats of the current 4-feat group)
    const int srow  = t >> 1;         // 0..127
    const int fpair = t & 1;          // which 2-feat half
    const float* xp = x + (size_t)(row_base + srow) * IN_F + kp * 128 + fpair * 2;
    const int sboff = srow * AROWH + fpair * 24;

    const int ntg0 = cg * 4 + wc * 2;
    const uint4* Bp0 = (const uint4*)g_Wb + (size_t)ntg0 * K16S * 64 + lane
                       + (size_t)(kp * 96) * 64;   // k16 base of this K-quarter
    const uint4* Bp1 = Bp0 + (size_t)K16S * 64;

    const int ar0 = (wr * 64 + ln31) * AROWH + half * 8;
    const int ar1 = (wr * 64 + 32 + ln31) * AROWH + half * 8;

    f32x16 acc[2][2] = {};

    // prologue: stage group 0 into buf0
    float2 xv = *(const float2*)xp;
    stage2(xv, &As[sboff]);
    xv = *(const float2*)(xp + 4);    // group 1
    __syncthreads();

    #pragma unroll 2
    for (int gi = 0; gi < 32; ++gi) {
        // B frags for this group (3 k16) — latency covered by a-reads + stage
        uint4 breg[3][2];
        #pragma unroll
        for (int ks = 0; ks < 3; ++ks) {
            breg[ks][0] = Bp0[(size_t)(gi * 3 + ks) * 64];
            breg[ks][1] = Bp1[(size_t)(gi * 3 + ks) * 64];
        }
        // A frags from current buffer (published by last iter's barrier)
        const int cur = (gi & 1) * ABUFH;
        uint4 a0[3], a1[3];
        #pragma unroll
        for (int ks = 0; ks < 3; ++ks) {
            a0[ks] = *(const uint4*)&As[cur + ar0 + ks * 16];
            a1[ks] = *(const uint4*)&As[cur + ar1 + ks * 16];
        }
        // stage next group into the other buffer (overlaps MFMA across waves)
        const int nxt = ((gi + 1) & 1) * ABUFH;
        if (gi < 31) stage2(xv, &As[nxt + sboff]);
        const int gn = (gi + 2 < 32) ? gi + 2 : 31;   // clamped x prefetch
        xv = *(const float2*)(xp + gn * 4);

        #pragma unroll
        for (int ks = 0; ks < 3; ++ks) {
            bf16x8 af0 = __builtin_bit_cast(bf16x8, a0[ks]);
            bf16x8 af1 = __builtin_bit_cast(bf16x8, a1[ks]);
            bf16x8 bf0 = __builtin_bit_cast(bf16x8, breg[ks][0]);
            bf16x8 bf1 = __builtin_bit_cast(bf16x8, breg[ks][1]);
            acc[0][0] = __builtin_amdgcn_mfma_f32_32x32x16_bf16(af0, bf0, acc[0][0], 0, 0, 0);
            acc[0][1] = __builtin_amdgcn_mfma_f32_32x32x16_bf16(af0, bf1, acc[0][1], 0, 0, 0);
            acc[1][0] = __builtin_amdgcn_mfma_f32_32x32x16_bf16(af1, bf0, acc[1][0], 0, 0, 0);
            acc[1][1] = __builtin_amdgcn_mfma_f32_32x32x16_bf16(af1, bf1, acc[1][1], 0, 0, 0);
        }
        __syncthreads();              // publish nxt; cur reads done; ~0 vmem outstanding
    }

    // epilogue: C layout col=lane&31, row=(reg&3)+8*(reg>>2)+4*(lane>>5)
    #pragma unroll
    for (int mt = 0; mt < 2; ++mt) {
        #pragma unroll
        for (int nt2 = 0; nt2 < 2; ++nt2) {
            int rb = row_base + wr * 64 + mt * 32 + 4 * half;
            int cc = cg * 128 + wc * 64 + nt2 * 32 + ln31;
            #pragma unroll
            for (int reg = 0; reg < 16; ++reg) {
                int rr = rb + (reg & 3) + 8 * (reg >> 2);
                unsafeAtomicAdd(&out[(size_t)rr * OUT_F + cc], acc[mt][nt2][reg]);
            }
        }
    }
}

extern "C" void kernel_launch(void* const* d_in, const int* in_sizes, int n_in,
                              void* d_out, int out_size, void* d_ws, size_t ws_size,
                              hipStream_t stream) {
    const float* x  = (const float*)d_in[0];
    const float* bw = (const float*)d_in[1];
    const float* sw = (const float*)d_in[2];
    float* out = (float*)d_out;
    hipLaunchKernelGGL(prep_weights, dim3(1024), dim3(256), 0, stream, bw, sw, out);
    hipLaunchKernelGGL(kan_gemm, dim3(1024), dim3(256), 0, stream, x, out);
}